// Round 1
// baseline (388.669 us; speedup 1.0000x reference)
//
#include <hip/hip_runtime.h>

// VectorQuantizer: B=16, T=8192, D=64, K=1024
//   quantized[B,T,D] fp32  ++  indices[B,T] written as float32 values
#define M_TOK   131072    // B*T
#define DIM     64
#define KCODES  1024
#define MT      64        // tokens per block
#define KC      128       // codes per LDS chunk
#define NCH     (KCODES / KC)   // 8

// ---- e2[k] = sum_d w[k][d]^2 ----
__global__ __launch_bounds__(256) void e2_kernel(const float* __restrict__ w,
                                                 float* __restrict__ e2) {
    int k = blockIdx.x * 256 + threadIdx.x;
    if (k < KCODES) {
        const float4* r = (const float4*)(w + (size_t)k * DIM);
        float s = 0.f;
#pragma unroll
        for (int i = 0; i < DIM / 4; ++i) {
            float4 v = r[i];
            s = fmaf(v.x, v.x, s);
            s = fmaf(v.y, v.y, s);
            s = fmaf(v.z, v.z, s);
            s = fmaf(v.w, v.w, s);
        }
        e2[k] = s;
    }
}

// ---- main fused kernel: distances + argmin + gather ----
__global__ __launch_bounds__(256) void vq_kernel(const float* __restrict__ x,
                                                 const float* __restrict__ w,
                                                 const float* __restrict__ e2g,
                                                 float* __restrict__ out) {
    // LDS layout (floats):
    //   [0, 4096)        xT[d][t]   : 64 x 64          (16 KB)  -- aliased by reduction at end
    //   [4096, 12288)    wT[d][k]   : 64 x 128         (32 KB)
    //   [12288, 13312)   e2 table   : 1024             (4 KB)
    __shared__ float smem[13312];
    __shared__ int   ldsIdx[MT];
    float* ldsX = smem;
    float* ldsW = smem + 4096;
    float* ldsE = smem + 12288;
    float* redV = smem;                // 64 tokens x 16 code-groups (aliases xT)
    int*   redI = (int*)(smem + 1024); // next 1024 floats of xT region

    const int tid = threadIdx.x;
    const int blk = blockIdx.x;
    const int tg  = tid & 15;   // token group: tokens tg*4 .. tg*4+3
    const int cg  = tid >> 4;   // code group : codes  cg*8 .. cg*8+7 (within chunk)

    // ---- stage x tile transposed: xT[d][t] ----
    {
        int t  = tid & 63;
        int d0 = (tid >> 6) * 16;
        const float* xb = x + ((size_t)blk * MT + t) * DIM + d0;
#pragma unroll
        for (int m = 0; m < 4; ++m) {
            float4 v = *(const float4*)(xb + 4 * m);
            int d = d0 + 4 * m;
            ldsX[(d + 0) * MT + t] = v.x;
            ldsX[(d + 1) * MT + t] = v.y;
            ldsX[(d + 2) * MT + t] = v.z;
            ldsX[(d + 3) * MT + t] = v.w;
        }
    }
    // ---- stage e2 table ----
    {
        float4 v = ((const float4*)e2g)[tid];
        *(float4*)&ldsE[tid * 4] = v;
    }

    float bestV[4] = {1e30f, 1e30f, 1e30f, 1e30f};
    int   bestI[4] = {0, 0, 0, 0};

    for (int c = 0; c < NCH; ++c) {
        __syncthreads();   // previous chunk fully consumed before restaging wT
        // ---- stage w chunk transposed: wT[d][k], k in [c*128, c*128+128) ----
        {
            int d0 = (tid >> 6) * 16;
#pragma unroll
            for (int i = 0; i < 2; ++i) {
                int kl = (tid & 63) + 64 * i;
                const float* wb = w + ((size_t)(c * KC + kl)) * DIM + d0;
#pragma unroll
                for (int m = 0; m < 4; ++m) {
                    float4 v = *(const float4*)(wb + 4 * m);
                    int d = d0 + 4 * m;
                    ldsW[(d + 0) * KC + kl] = v.x;
                    ldsW[(d + 1) * KC + kl] = v.y;
                    ldsW[(d + 2) * KC + kl] = v.z;
                    ldsW[(d + 3) * KC + kl] = v.w;
                }
            }
        }
        __syncthreads();

        float acc[4][8];
#pragma unroll
        for (int ti = 0; ti < 4; ++ti)
#pragma unroll
            for (int j = 0; j < 8; ++j) acc[ti][j] = 0.f;

#pragma unroll 4
        for (int d = 0; d < DIM; ++d) {
            float4 xv = *(const float4*)&ldsX[d * MT + tg * 4];
            float4 w0 = *(const float4*)&ldsW[d * KC + cg * 8];
            float4 w1 = *(const float4*)&ldsW[d * KC + cg * 8 + 4];
            float xr[4] = {xv.x, xv.y, xv.z, xv.w};
            float wr[8] = {w0.x, w0.y, w0.z, w0.w, w1.x, w1.y, w1.z, w1.w};
#pragma unroll
            for (int ti = 0; ti < 4; ++ti)
#pragma unroll
                for (int j = 0; j < 8; ++j)
                    acc[ti][j] = fmaf(xr[ti], wr[j], acc[ti][j]);
        }

        // epilogue: dist = e2[k] - 2*dot  (||x||^2 is argmin-invariant)
#pragma unroll
        for (int j = 0; j < 8; ++j) {
            int gk = c * KC + cg * 8 + j;
            float ev = ldsE[gk];
#pragma unroll
            for (int ti = 0; ti < 4; ++ti) {
                float dv = fmaf(-2.f, acc[ti][j], ev);
                if (dv < bestV[ti]) { bestV[ti] = dv; bestI[ti] = gk; }
            }
        }
    }

    // ---- cross-thread argmin reduction (16 code-groups per token) ----
    __syncthreads();   // main loop done; safe to alias xT region
#pragma unroll
    for (int ti = 0; ti < 4; ++ti) {
        int tl = tg * 4 + ti;
        redV[tl * 16 + cg] = bestV[ti];
        redI[tl * 16 + cg] = bestI[ti];
    }
    __syncthreads();
    if (tid < MT) {
        float bv = redV[tid * 16];
        int   bi = redI[tid * 16];
#pragma unroll
        for (int m = 1; m < 16; ++m) {
            float v = redV[tid * 16 + m];
            int   i = redI[tid * 16 + m];
            if (v < bv || (v == bv && i < bi)) { bv = v; bi = i; }
        }
        ldsIdx[tid] = bi;
        // indices written as float32 values (harness reads whole d_out as fp32)
        out[(size_t)M_TOK * DIM + (size_t)blk * MT + tid] = (float)bi;
    }
    __syncthreads();

    // ---- gather: quantized[t] = weight[best_idx[t]] ----
    {
        int t2   = tid >> 2;     // token 0..63
        int part = tid & 3;      // 16-float slice
        int gi = ldsIdx[t2];
        const float4* wr = (const float4*)(w + (size_t)gi * DIM + part * 16);
        float4* orow = (float4*)(out + ((size_t)blk * MT + t2) * DIM + part * 16);
#pragma unroll
        for (int j = 0; j < 4; ++j) orow[j] = wr[j];
    }
}

extern "C" void kernel_launch(void* const* d_in, const int* in_sizes, int n_in,
                              void* d_out, int out_size, void* d_ws, size_t ws_size,
                              hipStream_t stream) {
    const float* x = (const float*)d_in[0];     // [B,T,D,1] fp32, contiguous [M][D]
    const float* w = (const float*)d_in[1];     // [K,D] fp32
    float* out = (float*)d_out;
    float* e2  = (float*)d_ws;                  // 1024 floats scratch

    e2_kernel<<<(KCODES + 255) / 256, 256, 0, stream>>>(w, e2);
    vq_kernel<<<M_TOK / MT, 256, 0, stream>>>(x, w, e2, out);
}

// Round 2
// 188.029 us; speedup vs baseline: 2.0671x; 2.0671x over previous
//
#include <hip/hip_runtime.h>

// VectorQuantizer on MFMA: B=16,T=8192,D=64,K=1024
// out = [quantized 131072x64 f32][indices 131072 as f32]
#define MTOK  131072
#define DIMD  64
#define KCODE 1024
#define TPB   128          // tokens per block
#define CHK   64           // codes per chunk
#define NCHK  16
#define ROWE  136          // LDS row: 64 hi + 64 lo + 8 pad (bf16 elems)

typedef __bf16 bf16x8 __attribute__((ext_vector_type(8)));
typedef __bf16 bf16x4 __attribute__((ext_vector_type(4)));
typedef float  f32x4  __attribute__((ext_vector_type(4)));

__device__ inline f32x4 mfma16(bf16x8 a, bf16x8 b, f32x4 c) {
    return __builtin_amdgcn_mfma_f32_16x16x32_bf16(a, b, c, 0, 0, 0);
}

// ---- prep: split w into hi/lo bf16, compute e2 (round-1 fma order) and -e2/2 ----
__global__ __launch_bounds__(256) void prep_kernel(
    const float* __restrict__ w, __bf16* __restrict__ wh, __bf16* __restrict__ wl,
    float* __restrict__ e2n, float* __restrict__ e2) {
    int k = blockIdx.x * 256 + threadIdx.x;
    if (k >= KCODE) return;
    const float4* row = (const float4*)(w + (size_t)k * DIMD);
    float s = 0.f;
#pragma unroll
    for (int i = 0; i < 16; ++i) {
        float4 v = row[i];
        __bf16 h0 = (__bf16)v.x, h1 = (__bf16)v.y, h2 = (__bf16)v.z, h3 = (__bf16)v.w;
        bf16x4 hv = {h0, h1, h2, h3};
        bf16x4 lv = {(__bf16)(v.x - (float)h0), (__bf16)(v.y - (float)h1),
                     (__bf16)(v.z - (float)h2), (__bf16)(v.w - (float)h3)};
        *(bf16x4*)(wh + (size_t)k * DIMD + i * 4) = hv;
        *(bf16x4*)(wl + (size_t)k * DIMD + i * 4) = lv;
        s = fmaf(v.x, v.x, s); s = fmaf(v.y, v.y, s);
        s = fmaf(v.z, v.z, s); s = fmaf(v.w, v.w, s);
    }
    e2[k] = s;
    e2n[k] = -0.5f * s;
}

__global__ __launch_bounds__(256, 2) void vq_main(
    const float* __restrict__ x, const float* __restrict__ wfull,
    const __bf16* __restrict__ wh, const __bf16* __restrict__ wl,
    const float* __restrict__ e2n_g, const float* __restrict__ e2_g,
    float* __restrict__ out) {

    __shared__ __align__(16) __bf16 ldsX[TPB * ROWE];   // 34816 B
    __shared__ __align__(16) __bf16 ldsW[CHK * ROWE];   // 17408 B
    __shared__ __align__(16) float  ldsE[KCODE];        // 4096 B  (-e2/2)
    __shared__ int   ldsIdx[TPB];
    __shared__ float redV[256];
    __shared__ int   redI[256];
    __shared__ int   nflag;
    __shared__ int   flist[TPB];

    const int tid  = threadIdx.x;
    const int blk  = blockIdx.x;
    const int lane = tid & 63;
    const int wv   = tid >> 6;        // wave 0..3 -> tokens wv*32..+32
    const int quad = lane >> 4;
    const int m    = lane & 15;

    // ---- stage x tile: fp32 -> (hi,lo) bf16 rows [hi64|lo64] ----
    {
        const float4* xb = (const float4*)(x + (size_t)blk * TPB * DIMD);
#pragma unroll
        for (int j = 0; j < 8; ++j) {
            int s  = tid + j * 256;          // float4 slot 0..2047 (coalesced)
            int tk = s >> 4;
            int d4 = (s & 15) * 4;
            float4 v = xb[s];
            __bf16 h0 = (__bf16)v.x, h1 = (__bf16)v.y, h2 = (__bf16)v.z, h3 = (__bf16)v.w;
            bf16x4 hv = {h0, h1, h2, h3};
            bf16x4 lv = {(__bf16)(v.x - (float)h0), (__bf16)(v.y - (float)h1),
                         (__bf16)(v.z - (float)h2), (__bf16)(v.w - (float)h3)};
            *(bf16x4*)&ldsX[tk * ROWE + d4]      = hv;
            *(bf16x4*)&ldsX[tk * ROWE + 64 + d4] = lv;
        }
    }
    // ---- stage -e2/2 table ----
    ((f32x4*)ldsE)[tid] = ((const f32x4*)e2n_g)[tid];
    if (tid == 0) nflag = 0;

    // ---- prefetch w chunk 0 (already bf16 from prep) ----
    const int wc = tid >> 2, wp = tid & 3;   // code-in-chunk, 16-elem part
    uint4 pf0, pf1, pf2, pf3;
    {
        const uint4* gh = (const uint4*)(wh + (size_t)wc * DIMD);
        const uint4* gl = (const uint4*)(wl + (size_t)wc * DIMD);
        pf0 = gh[wp * 2]; pf1 = gh[wp * 2 + 1];
        pf2 = gl[wp * 2]; pf3 = gl[wp * 2 + 1];
    }
    __syncthreads();
    {
        *(uint4*)&ldsW[wc * ROWE + wp * 16]          = pf0;
        *(uint4*)&ldsW[wc * ROWE + wp * 16 + 8]      = pf1;
        *(uint4*)&ldsW[wc * ROWE + 64 + wp * 16]     = pf2;
        *(uint4*)&ldsW[wc * ROWE + 64 + wp * 16 + 8] = pf3;
    }
    __syncthreads();

    // ---- hoist x fragments: bx[token-group][k-window], windows: hi0,hi1,lo0,lo1 ----
    bf16x8 bx[2][4];
#pragma unroll
    for (int tg = 0; tg < 2; ++tg)
#pragma unroll
        for (int win = 0; win < 4; ++win)
            bx[tg][win] = *(const bf16x8*)&ldsX[(wv * 32 + tg * 16 + m) * ROWE + win * 32 + quad * 8];

    float b1[4][2], b2[4][2];
    int   i1[4][2];
#pragma unroll
    for (int cg = 0; cg < 4; ++cg)
#pragma unroll
        for (int tg = 0; tg < 2; ++tg) { b1[cg][tg] = -3e38f; b2[cg][tg] = -3e38f; i1[cg][tg] = 0; }

    for (int ck = 0; ck < NCHK; ++ck) {
        // prefetch next w chunk into regs (hides global latency under MFMA)
        uint4 n0, n1, n2, n3;
        if (ck + 1 < NCHK) {
            const uint4* gh = (const uint4*)(wh + ((size_t)(ck + 1) * CHK + wc) * DIMD);
            const uint4* gl = (const uint4*)(wl + ((size_t)(ck + 1) * CHK + wc) * DIMD);
            n0 = gh[wp * 2]; n1 = gh[wp * 2 + 1];
            n2 = gl[wp * 2]; n3 = gl[wp * 2 + 1];
        }

        // acc init = -e2[k]/2  ->  acc = dot - e2/2, argmax(acc) == argmin(dist)
        f32x4 acc[4][2];
#pragma unroll
        for (int cg = 0; cg < 4; ++cg) {
            f32x4 e = *(const f32x4*)&ldsE[ck * 64 + cg * 16 + quad * 4];
            acc[cg][0] = e; acc[cg][1] = e;
        }

#pragma unroll
        for (int cg = 0; cg < 4; ++cg) {
            const __bf16* ar = &ldsW[(cg * 16 + m) * ROWE + quad * 8];
            bf16x8 a0 = *(const bf16x8*)(ar);         // w_hi d0-31
            bf16x8 a1 = *(const bf16x8*)(ar + 32);    // w_hi d32-63
            bf16x8 a2 = *(const bf16x8*)(ar + 64);    // w_lo d0-31
            bf16x8 a3 = *(const bf16x8*)(ar + 96);    // w_lo d32-63
#pragma unroll
            for (int tg = 0; tg < 2; ++tg) {
                f32x4 t = acc[cg][tg];
                t = mfma16(a0, bx[tg][0], t);   // hi*hi
                t = mfma16(a1, bx[tg][1], t);
                t = mfma16(a0, bx[tg][2], t);   // w_hi * x_lo
                t = mfma16(a1, bx[tg][3], t);
                t = mfma16(a2, bx[tg][0], t);   // w_lo * x_hi
                t = mfma16(a3, bx[tg][1], t);
                acc[cg][tg] = t;
            }
        }

        // trackers: per-tile best (value+idx) and 2nd-best value (med3) — argmax sense
#pragma unroll
        for (int cg = 0; cg < 4; ++cg)
#pragma unroll
            for (int tg = 0; tg < 2; ++tg)
#pragma unroll
                for (int r = 0; r < 4; ++r) {
                    float a   = acc[cg][tg][r];
                    int  idxv = ck * 64 + cg * 16 + quad * 4 + r;
                    bool gt   = a > b1[cg][tg];
                    i1[cg][tg] = gt ? idxv : i1[cg][tg];
                    b2[cg][tg] = __builtin_amdgcn_fmed3f(a, b1[cg][tg], b2[cg][tg]);
                    b1[cg][tg] = fmaxf(a, b1[cg][tg]);
                }

        __syncthreads();   // all waves done reading ldsW(ck)
        if (ck + 1 < NCHK) {
            *(uint4*)&ldsW[wc * ROWE + wp * 16]          = n0;
            *(uint4*)&ldsW[wc * ROWE + wp * 16 + 8]      = n1;
            *(uint4*)&ldsW[wc * ROWE + 64 + wp * 16]     = n2;
            *(uint4*)&ldsW[wc * ROWE + 64 + wp * 16 + 8] = n3;
        }
        __syncthreads();
    }

    // ---- merge: across code-groups, then across quads (lanes m,m+16,m+32,m+48) ----
#pragma unroll
    for (int tg = 0; tg < 2; ++tg) {
        float B1 = b1[0][tg], B2 = b2[0][tg];
        int   I1 = i1[0][tg];
#pragma unroll
        for (int cg = 1; cg < 4; ++cg) {
            float nb1 = b1[cg][tg], nb2 = b2[cg][tg];
            bool gt = nb1 > B1;                         // strict: ties keep lower code
            B2 = fmaxf(fminf(nb1, B1), fmaxf(nb2, B2)); // 2nd-largest of union
            I1 = gt ? i1[cg][tg] : I1;
            B1 = fmaxf(nb1, B1);
        }
#pragma unroll
        for (int mask = 16; mask <= 32; mask <<= 1) {
            float ob1 = __shfl_xor(B1, mask);
            float ob2 = __shfl_xor(B2, mask);
            int   oi  = __shfl_xor(I1, mask);
            bool take = (ob1 > B1) || (ob1 == B1 && oi < I1);
            B2 = fmaxf(fminf(ob1, B1), fmaxf(ob2, B2));
            I1 = take ? oi : I1;
            B1 = fmaxf(ob1, B1);
        }
        if (quad == 0) {
            int tl = wv * 32 + tg * 16 + m;
            ldsIdx[tl] = I1;
            // dist-gap = 2*(B1-B2); flag anything < 4e-3 (worst-case err bound ~1e-3)
            if (B1 - B2 < 2e-3f) {
                int p = atomicAdd(&nflag, 1);
                flist[p] = tl;
            }
        }
    }
    __syncthreads();

    // ---- exact fp32 rescan of flagged tokens (identical math to round-1 kernel) ----
    int nf = nflag;
    for (int f = 0; f < nf; ++f) {
        int tl = flist[f];
        const float4* xr = (const float4*)(x + (size_t)(blk * TPB + tl) * DIMD);
        float bv = 3e38f; int bi = 0;
#pragma unroll
        for (int j = 0; j < 4; ++j) {
            int k = tid * 4 + j;
            const float4* wr = (const float4*)(wfull + (size_t)k * DIMD);
            float s = 0.f;
#pragma unroll
            for (int i = 0; i < 16; ++i) {
                float4 xv = xr[i];
                float4 wv4 = wr[i];
                s = fmaf(xv.x, wv4.x, s); s = fmaf(xv.y, wv4.y, s);
                s = fmaf(xv.z, wv4.z, s); s = fmaf(xv.w, wv4.w, s);
            }
            float dv = fmaf(-2.f, s, e2_g[k]);
            if (dv < bv) { bv = dv; bi = k; }           // ties -> lower k
        }
        redV[tid] = bv; redI[tid] = bi;
        __syncthreads();
        if (tid == 0) {
            float v = redV[0]; int b = redI[0];
            for (int t2 = 1; t2 < 256; ++t2)
                if (redV[t2] < v) { v = redV[t2]; b = redI[t2]; }  // lower thread = lower codes
            ldsIdx[tl] = b;
        }
        __syncthreads();
    }

    // ---- outputs: indices (as f32) + gathered codebook rows ----
    if (tid < TPB)
        out[(size_t)MTOK * DIMD + (size_t)blk * TPB + tid] = (float)ldsIdx[tid];
    {
        int tk = tid >> 1, half = tid & 1;
        int gi = ldsIdx[tk];
        const float4* wr = (const float4*)(wfull + (size_t)gi * DIMD + half * 32);
        float4* o = (float4*)(out + (size_t)(blk * TPB + tk) * DIMD + half * 32);
#pragma unroll
        for (int j = 0; j < 8; ++j) o[j] = wr[j];
    }
}

extern "C" void kernel_launch(void* const* d_in, const int* in_sizes, int n_in,
                              void* d_out, int out_size, void* d_ws, size_t ws_size,
                              hipStream_t stream) {
    const float* x = (const float*)d_in[0];
    const float* w = (const float*)d_in[1];
    float* out = (float*)d_out;

    // ws: [w_hi 128K][w_lo 128K][e2n 4K][e2 4K]
    __bf16* wh  = (__bf16*)d_ws;
    __bf16* wl  = (__bf16*)((char*)d_ws + 131072);
    float*  e2n = (float*)((char*)d_ws + 262144);
    float*  e2  = (float*)((char*)d_ws + 266240);

    prep_kernel<<<KCODE / 256, 256, 0, stream>>>(w, wh, wl, e2n, e2);
    vq_main<<<MTOK / TPB, 256, 0, stream>>>(x, w, wh, wl, e2n, e2, out);
}

// Round 3
// 174.740 us; speedup vs baseline: 2.2243x; 1.0760x over previous
//
#include <hip/hip_runtime.h>

// VectorQuantizer: B=16,T=8192,D=64,K=1024
// out = [quantized 131072x64 f32][indices 131072 as f32]
#define MTOK  131072
#define DIMD  64
#define KCODE 1024
#define TPB   256        // tokens per block = 4 waves x 64 tokens
#define CHK   128        // codes per chunk
#define NCHK  8
#define CBPC  8          // 16-code blocks per chunk

typedef __bf16 bf16x8 __attribute__((ext_vector_type(8)));
typedef float  f32x4  __attribute__((ext_vector_type(4)));

__device__ __forceinline__ f32x4 mfma16(bf16x8 a, bf16x8 b, f32x4 c) {
    return __builtin_amdgcn_mfma_f32_16x16x32_bf16(a, b, c, 0, 0, 0);
}

// async global->LDS, 16B per lane; LDS dest is wave-uniform base + lane*16
__device__ __forceinline__ void g2l16(const void* g, void* l) {
    __builtin_amdgcn_global_load_lds(
        (const __attribute__((address_space(1))) unsigned int*)g,
        (__attribute__((address_space(3))) unsigned int*)l, 16, 0, 0);
}

// ---- prep: pack W into MFMA-fragment order + e2 tables ----
// wpk layout: [cb 0..63][win 0..3][lane 0..63][8 bf16] ; win: 0=hi d0-31, 1=hi d32-63, 2=lo d0-31, 3=lo d32-63
// fragment (cb,win,lane=(q,m)) = part(w[cb*16+m][(win&1)*32 + q*8 .. +8])
__global__ __launch_bounds__(256) void prep_kernel(
    const float* __restrict__ w, __bf16* __restrict__ wpk,
    float* __restrict__ e2n, float* __restrict__ e2) {
    int cb  = blockIdx.x;            // 0..63
    int tid = threadIdx.x;
    int win = tid >> 6, lane = tid & 63;
    int q = lane >> 4, m = lane & 15;
    int k = cb * 16 + m;
    int d0 = (win & 1) * 32 + q * 8;
    const float* src = w + (size_t)k * DIMD + d0;
    float4 v0 = *(const float4*)(src);
    float4 v1 = *(const float4*)(src + 4);
    float f[8] = {v0.x, v0.y, v0.z, v0.w, v1.x, v1.y, v1.z, v1.w};
    bf16x8 o;
#pragma unroll
    for (int j = 0; j < 8; ++j) {
        __bf16 h = (__bf16)f[j];
        o[j] = (win < 2) ? h : (__bf16)(f[j] - (float)h);
    }
    *(bf16x8*)(wpk + ((size_t)(cb * 4 + win) * 64 + lane) * 8) = o;

    if (tid < 16) {   // e2 in exact round-1 fma order
        int k2 = cb * 16 + tid;
        const float4* row = (const float4*)(w + (size_t)k2 * DIMD);
        float s = 0.f;
#pragma unroll
        for (int i = 0; i < 16; ++i) {
            float4 v = row[i];
            s = fmaf(v.x, v.x, s); s = fmaf(v.y, v.y, s);
            s = fmaf(v.z, v.z, s); s = fmaf(v.w, v.w, s);
        }
        e2[k2]  = s;
        e2n[k2] = -0.5f * s;
    }
}

__global__ __launch_bounds__(256, 2) void vq_main(
    const float* __restrict__ x, const float* __restrict__ wfull,
    const __bf16* __restrict__ wpk, const float* __restrict__ e2n_g,
    const float* __restrict__ e2_g, float* __restrict__ out) {

    __shared__ __align__(16) __bf16 ldsW[2][CBPC * 4 * 64 * 8];  // 2 x 32 KB
    __shared__ __align__(16) float  ldsE[KCODE];                 // -e2/2, 4 KB
    __shared__ int   ldsIdx[TPB];
    __shared__ int   flist[TPB];
    __shared__ float redV[256];
    __shared__ int   redI[256];
    __shared__ int   nflag;

    const int tid  = threadIdx.x;
    const int blk  = blockIdx.x;
    const int lane = tid & 63;
    const int wv   = tid >> 6;      // wave -> tokens wv*64..+64
    const int q    = lane >> 4;
    const int m    = lane & 15;

    // ---- issue async stage of chunk 0 into buf 0 (overlaps x-frag setup) ----
    {
        const char* gsrc = (const char*)wpk + (size_t)wv * 8192 + (size_t)lane * 16;
        char* ldst = (char*)&ldsW[0][0] + wv * 8192 + lane * 16;
#pragma unroll
        for (int j = 0; j < 8; ++j)
            g2l16(gsrc + j * 1024, ldst + j * 1024);
    }
    ((f32x4*)ldsE)[tid] = ((const f32x4*)e2n_g)[tid];
    if (tid == 0) nflag = 0;

    // ---- x fragments straight from global, hi/lo split in registers ----
    bf16x8 bx[4][4];
#pragma unroll
    for (int tg = 0; tg < 4; ++tg) {
        const float* xr = x + ((size_t)blk * TPB + wv * 64 + tg * 16 + m) * DIMD;
#pragma unroll
        for (int h = 0; h < 2; ++h) {             // h=0: dims q*8, h=1: 32+q*8
            float4 v0 = *(const float4*)(xr + h * 32 + q * 8);
            float4 v1 = *(const float4*)(xr + h * 32 + q * 8 + 4);
            float f[8] = {v0.x, v0.y, v0.z, v0.w, v1.x, v1.y, v1.z, v1.w};
            bf16x8 hi, lo;
#pragma unroll
            for (int j = 0; j < 8; ++j) {
                __bf16 hh = (__bf16)f[j];
                hi[j] = hh;
                lo[j] = (__bf16)(f[j] - (float)hh);
            }
            bx[tg][h]     = hi;
            bx[tg][2 + h] = lo;
        }
    }

    float b1[4], b2[4]; int i1[4];
#pragma unroll
    for (int tg = 0; tg < 4; ++tg) { b1[tg] = -3e38f; b2[tg] = -3e38f; i1[tg] = 0; }

    __syncthreads();   // chunk 0 resident (barrier drains vmcnt), ldsE ready

    for (int ck = 0; ck < NCHK; ++ck) {
        if (ck + 1 < NCHK) {   // prefetch next chunk, full chunk of MFMA ahead
            const char* gsrc = (const char*)wpk + (size_t)(ck + 1) * 32768
                             + (size_t)wv * 8192 + (size_t)lane * 16;
            char* ldst = (char*)&ldsW[(ck + 1) & 1][0] + wv * 8192 + lane * 16;
#pragma unroll
            for (int j = 0; j < 8; ++j)
                g2l16(gsrc + j * 1024, ldst + j * 1024);
        }
        const __bf16* wb = &ldsW[ck & 1][0];
#pragma unroll
        for (int cb = 0; cb < CBPC; ++cb) {
            // lane-contiguous ds_read_b128 — zero bank conflicts
            bf16x8 a0 = *(const bf16x8*)(wb + (size_t)(cb * 4 + 0) * 512 + lane * 8);
            bf16x8 a1 = *(const bf16x8*)(wb + (size_t)(cb * 4 + 1) * 512 + lane * 8);
            bf16x8 a2 = *(const bf16x8*)(wb + (size_t)(cb * 4 + 2) * 512 + lane * 8);
            bf16x8 a3 = *(const bf16x8*)(wb + (size_t)(cb * 4 + 3) * 512 + lane * 8);
            f32x4 e = *(const f32x4*)&ldsE[ck * CHK + cb * 16 + q * 4];
            int base = ck * CHK + cb * 16 + q * 4;
#pragma unroll
            for (int tg = 0; tg < 4; ++tg) {
                f32x4 t = e;                      // acc = dot - e2/2 ; argmax == argmin dist
                t = mfma16(a0, bx[tg][0], t);     // hi*hi d0-31
                t = mfma16(a1, bx[tg][1], t);     // hi*hi d32-63
                t = mfma16(a0, bx[tg][2], t);     // w_hi*x_lo
                t = mfma16(a1, bx[tg][3], t);
                t = mfma16(a2, bx[tg][0], t);     // w_lo*x_hi
                t = mfma16(a3, bx[tg][1], t);
#pragma unroll
                for (int r = 0; r < 4; ++r) {
                    float a  = t[r];
                    int idxv = base + r;
                    bool gt  = a > b1[tg];        // strict: ties keep lower code
                    i1[tg] = gt ? idxv : i1[tg];
                    b2[tg] = __builtin_amdgcn_fmed3f(a, b1[tg], b2[tg]);
                    b1[tg] = fmaxf(a, b1[tg]);
                }
            }
        }
        __syncthreads();   // buf (ck&1) free for prefetch ck+2; buf (ck+1)&1 landed
    }

    // ---- cross-quad merge (lanes m, m+16, m+32, m+48 hold disjoint code sets) ----
#pragma unroll
    for (int tg = 0; tg < 4; ++tg) {
        float B1 = b1[tg], B2 = b2[tg]; int I1 = i1[tg];
#pragma unroll
        for (int mask = 16; mask <= 32; mask <<= 1) {
            float ob1 = __shfl_xor(B1, mask);
            float ob2 = __shfl_xor(B2, mask);
            int   oi  = __shfl_xor(I1, mask);
            bool take = (ob1 > B1) || (ob1 == B1 && oi < I1);
            B2 = fmaxf(fminf(ob1, B1), fmaxf(ob2, B2));
            I1 = take ? oi : I1;
            B1 = fmaxf(ob1, B1);
        }
        if (q == 0) {
            int tl = wv * 64 + tg * 16 + m;
            ldsIdx[tl] = I1;
            // dot-space gap; worst-case split error << 2e-3 (validated round 2)
            if (B1 - B2 < 2e-3f) { int p = atomicAdd(&nflag, 1); flist[p] = tl; }
        }
    }
    __syncthreads();

    // ---- exact fp32 rescan of flagged tokens (round-1 numerics) ----
    int nf = nflag;
    for (int f = 0; f < nf; ++f) {
        int tl = flist[f];
        const float4* xr = (const float4*)(x + (size_t)(blk * TPB + tl) * DIMD);
        float bv = 3e38f; int bi = 0;
#pragma unroll
        for (int j = 0; j < 4; ++j) {
            int k = tid * 4 + j;
            const float4* wr = (const float4*)(wfull + (size_t)k * DIMD);
            float s = 0.f;
#pragma unroll
            for (int i = 0; i < 16; ++i) {
                float4 xv = xr[i];
                float4 wv4 = wr[i];
                s = fmaf(xv.x, wv4.x, s); s = fmaf(xv.y, wv4.y, s);
                s = fmaf(xv.z, wv4.z, s); s = fmaf(xv.w, wv4.w, s);
            }
            float dv = fmaf(-2.f, s, e2_g[k]);
            if (dv < bv) { bv = dv; bi = k; }     // ties -> lower k
        }
        redV[tid] = bv; redI[tid] = bi;
        __syncthreads();
        if (tid == 0) {
            float v = redV[0]; int b = redI[0];
            for (int t2 = 1; t2 < 256; ++t2)
                if (redV[t2] < v) { v = redV[t2]; b = redI[t2]; }
            ldsIdx[tl] = b;
        }
        __syncthreads();
    }

    // ---- outputs: indices (as f32) + gathered codebook rows ----
    out[(size_t)MTOK * DIMD + (size_t)blk * TPB + tid] = (float)ldsIdx[tid];
    {
        int gi = ldsIdx[tid];
        const float4* wr = (const float4*)(wfull + (size_t)gi * DIMD);
        float4* o = (float4*)(out + ((size_t)blk * TPB + tid) * DIMD);
#pragma unroll
        for (int j = 0; j < 16; ++j) o[j] = wr[j];
    }
}

extern "C" void kernel_launch(void* const* d_in, const int* in_sizes, int n_in,
                              void* d_out, int out_size, void* d_ws, size_t ws_size,
                              hipStream_t stream) {
    const float* x = (const float*)d_in[0];
    const float* w = (const float*)d_in[1];
    float* out = (float*)d_out;

    // ws: [wpk 256K][e2n 4K][e2 4K]
    __bf16* wpk = (__bf16*)d_ws;
    float*  e2n = (float*)((char*)d_ws + 262144);
    float*  e2  = (float*)((char*)d_ws + 266240);

    prep_kernel<<<64, 256, 0, stream>>>(w, wpk, e2n, e2);
    vq_main<<<MTOK / TPB, 256, 0, stream>>>(x, w, wpk, e2n, e2, out);
}

// Round 4
// 162.823 us; speedup vs baseline: 2.3871x; 1.0732x over previous
//
#include <hip/hip_runtime.h>

// VectorQuantizer: B=16,T=8192,D=64,K=1024
// out = [quantized 131072x64 f32][indices 131072 as f32]
// Round 4: LDS-free. W fragments stream L2->registers, 2-deep reg ping-pong,
// zero barriers; ballot-driven per-wave exact-fp32 rescan for near-ties.
#define MTOK  131072
#define DIMD  64
#define KCODE 1024
#define TPB   256        // 4 waves x 64 tokens

typedef __bf16 bf16x8 __attribute__((ext_vector_type(8)));
typedef float  f32x4  __attribute__((ext_vector_type(4)));

__device__ __forceinline__ f32x4 mfma16(bf16x8 a, bf16x8 b, f32x4 c) {
    return __builtin_amdgcn_mfma_f32_16x16x32_bf16(a, b, c, 0, 0, 0);
}

// ---- prep: pack W into MFMA-fragment order + e2 tables (round-3 verified) ----
// wpk element offset = cb*2048 + win*512 + lane*8
// win: 0=hi d0-31, 1=hi d32-63, 2=lo d0-31, 3=lo d32-63 ; lane=(q,m): w[cb*16+m][(win&1)*32+q*8 ..+8]
__global__ __launch_bounds__(256) void prep_kernel(
    const float* __restrict__ w, __bf16* __restrict__ wpk,
    float* __restrict__ e2n, float* __restrict__ e2) {
    int cb  = blockIdx.x;            // 0..63
    int tid = threadIdx.x;
    int win = tid >> 6, lane = tid & 63;
    int q = lane >> 4, m = lane & 15;
    int k = cb * 16 + m;
    int d0 = (win & 1) * 32 + q * 8;
    const float* src = w + (size_t)k * DIMD + d0;
    float4 v0 = *(const float4*)(src);
    float4 v1 = *(const float4*)(src + 4);
    float f[8] = {v0.x, v0.y, v0.z, v0.w, v1.x, v1.y, v1.z, v1.w};
    bf16x8 o;
#pragma unroll
    for (int j = 0; j < 8; ++j) {
        __bf16 h = (__bf16)f[j];
        o[j] = (win < 2) ? h : (__bf16)(f[j] - (float)h);
    }
    *(bf16x8*)(wpk + ((size_t)(cb * 4 + win) * 64 + lane) * 8) = o;

    if (tid < 16) {   // e2 in exact round-1 fma order (matches np argmin, absmax=0)
        int k2 = cb * 16 + tid;
        const float4* row = (const float4*)(w + (size_t)k2 * DIMD);
        float s = 0.f;
#pragma unroll
        for (int i = 0; i < 16; ++i) {
            float4 v = row[i];
            s = fmaf(v.x, v.x, s); s = fmaf(v.y, v.y, s);
            s = fmaf(v.z, v.z, s); s = fmaf(v.w, v.w, s);
        }
        e2[k2]  = s;
        e2n[k2] = -0.5f * s;
    }
}

__global__ __launch_bounds__(256, 2) void vq_main(
    const float* __restrict__ x, const float* __restrict__ wfull,
    const __bf16* __restrict__ wpk, const float* __restrict__ e2n_g,
    const float* __restrict__ e2_g, float* __restrict__ out) {

    const int tid  = threadIdx.x;
    const int blk  = blockIdx.x;
    const int lane = tid & 63;
    const int wv   = tid >> 6;      // wave -> tokens wv*64..+64
    const int q    = lane >> 4;
    const int m    = lane & 15;

    // ---- x fragments straight from global, hi/lo split in registers ----
    bf16x8 bx[4][4];
#pragma unroll
    for (int tg = 0; tg < 4; ++tg) {
        const float* xr = x + ((size_t)blk * TPB + wv * 64 + tg * 16 + m) * DIMD;
#pragma unroll
        for (int h = 0; h < 2; ++h) {
            float4 v0 = *(const float4*)(xr + h * 32 + q * 8);
            float4 v1 = *(const float4*)(xr + h * 32 + q * 8 + 4);
            float f[8] = {v0.x, v0.y, v0.z, v0.w, v1.x, v1.y, v1.z, v1.w};
            bf16x8 hi, lo;
#pragma unroll
            for (int j = 0; j < 8; ++j) {
                __bf16 hh = (__bf16)f[j];
                hi[j] = hh;
                lo[j] = (__bf16)(f[j] - (float)hh);
            }
            bx[tg][h]     = hi;
            bx[tg][2 + h] = lo;
        }
    }

    float b1[4], b2[4]; int i1[4];
#pragma unroll
    for (int tg = 0; tg < 4; ++tg) { b1[tg] = -3e38f; b2[tg] = -3e38f; i1[tg] = 0; }

    // acc = dot - e2/2 (C-init), argmax(acc) == argmin(dist); tracker keeps
    // top-1 (value+idx, strict > => ties keep lower code) and top-2 value (med3).
    auto step = [&](bf16x8 f0, bf16x8 f1, bf16x8 f2, bf16x8 f3, f32x4 ee, int cbase) {
#pragma unroll
        for (int tg = 0; tg < 4; ++tg) {
            f32x4 t = mfma16(f0, bx[tg][0], ee);   // w_hi*x_hi d0-31
            t = mfma16(f1, bx[tg][1], t);          // w_hi*x_hi d32-63
            t = mfma16(f0, bx[tg][2], t);          // w_hi*x_lo
            t = mfma16(f1, bx[tg][3], t);
            t = mfma16(f2, bx[tg][0], t);          // w_lo*x_hi
            t = mfma16(f3, bx[tg][1], t);
#pragma unroll
            for (int r = 0; r < 4; ++r) {
                float a   = t[r];
                int idxv  = cbase + q * 4 + r;
                bool gt   = a > b1[tg];
                i1[tg] = gt ? idxv : i1[tg];
                b2[tg] = __builtin_amdgcn_fmed3f(a, b1[tg], b2[tg]);
                b1[tg] = fmaxf(a, b1[tg]);
            }
        }
    };

    // ---- main loop: 64 code-blocks, W frags from L2, 2-deep reg ping-pong ----
    const __bf16* wb = wpk + lane * 8;     // lane-contiguous fragment base
    const float*  eb = e2n_g + q * 4;
    bf16x8 A0 = *(const bf16x8*)(wb + 0);
    bf16x8 A1 = *(const bf16x8*)(wb + 512);
    bf16x8 A2 = *(const bf16x8*)(wb + 1024);
    bf16x8 A3 = *(const bf16x8*)(wb + 1536);
    f32x4  EA = *(const f32x4*)(eb);

    for (int cb = 0; cb < 64; cb += 2) {
        const __bf16* pB = wb + (size_t)(cb + 1) * 2048;
        bf16x8 B0 = *(const bf16x8*)(pB + 0);
        bf16x8 B1 = *(const bf16x8*)(pB + 512);
        bf16x8 B2 = *(const bf16x8*)(pB + 1024);
        bf16x8 B3 = *(const bf16x8*)(pB + 1536);
        f32x4  EB = *(const f32x4*)(eb + (cb + 1) * 16);

        step(A0, A1, A2, A3, EA, cb * 16);

        if (cb + 2 < 64) {
            const __bf16* pA = wb + (size_t)(cb + 2) * 2048;
            A0 = *(const bf16x8*)(pA + 0);
            A1 = *(const bf16x8*)(pA + 512);
            A2 = *(const bf16x8*)(pA + 1024);
            A3 = *(const bf16x8*)(pA + 1536);
            EA = *(const f32x4*)(eb + (cb + 2) * 16);
        }
        step(B0, B1, B2, B3, EB, (cb + 1) * 16);
    }

    // ---- cross-quad merge: lanes m,m+16,m+32,m+48 hold disjoint code sets ----
    float B1f[4], B2f[4]; int I1f[4];
#pragma unroll
    for (int tg = 0; tg < 4; ++tg) {
        float B1 = b1[tg], B2 = b2[tg]; int I1 = i1[tg];
#pragma unroll
        for (int mask = 16; mask <= 32; mask <<= 1) {
            float ob1 = __shfl_xor(B1, mask);
            float ob2 = __shfl_xor(B2, mask);
            int   oi  = __shfl_xor(I1, mask);
            bool take = (ob1 > B1) || (ob1 == B1 && oi < I1);
            B2 = fmaxf(fminf(ob1, B1), fmaxf(ob2, B2));
            I1 = take ? oi : I1;
            B1 = fmaxf(ob1, B1);
        }
        B1f[tg] = B1; B2f[tg] = B2; I1f[tg] = I1;   // replicated across quads
    }

    // my token's index via shuffles (token of lane L = (L>>4)*16 + (L&15))
    int myidx;
    {
        int src = lane & 15;
        int v0 = __shfl(I1f[0], src);
        int v1 = __shfl(I1f[1], src);
        int v2 = __shfl(I1f[2], src);
        int v3 = __shfl(I1f[3], src);
        int tg4 = lane >> 4;
        myidx = (tg4 == 0) ? v0 : (tg4 == 1) ? v1 : (tg4 == 2) ? v2 : v3;
    }

    // ---- ballot-driven exact fp32 rescan of near-ties (round-1 numerics) ----
    for (int tg = 0; tg < 4; ++tg) {
        unsigned long long msk =
            __ballot((lane < 16) && (B1f[tg] - B2f[tg] < 2e-3f));
        while (msk) {
            int mm = __ffsll((unsigned long long)msk) - 1;
            msk &= msk - 1;
            int tloc = tg * 16 + mm;              // token within this wave
            const float4* xr = (const float4*)(x + ((size_t)blk * TPB + wv * 64 + tloc) * DIMD);
            float bv = 3e38f; int bi = 0;
            for (int j = 0; j < 16; ++j) {
                int k = lane * 16 + j;
                const float4* wr = (const float4*)(wfull + (size_t)k * DIMD);
                float s = 0.f;
#pragma unroll
                for (int i = 0; i < 16; ++i) {
                    float4 xv = xr[i], wv4 = wr[i];
                    s = fmaf(xv.x, wv4.x, s); s = fmaf(xv.y, wv4.y, s);
                    s = fmaf(xv.z, wv4.z, s); s = fmaf(xv.w, wv4.w, s);
                }
                float dv = fmaf(-2.f, s, e2_g[k]);
                if (dv < bv) { bv = dv; bi = k; }  // ties -> lower k
            }
#pragma unroll
            for (int mask2 = 1; mask2 <= 32; mask2 <<= 1) {
                float ov = __shfl_xor(bv, mask2);
                int   oi = __shfl_xor(bi, mask2);
                bool take = (ov < bv) || (ov == bv && oi < bi);
                bv = take ? ov : bv;
                bi = take ? oi : bi;
            }
            myidx = (lane == tloc) ? bi : myidx;
        }
    }

    // ---- outputs: index (as f32) + gathered codebook row ----
    out[(size_t)MTOK * DIMD + (size_t)blk * TPB + wv * 64 + lane] = (float)myidx;
    {
        const float4* wr = (const float4*)(wfull + (size_t)myidx * DIMD);
        float4* o = (float4*)(out + ((size_t)blk * TPB + wv * 64 + lane) * DIMD);
#pragma unroll
        for (int j = 0; j < 16; ++j) o[j] = wr[j];
    }
}

extern "C" void kernel_launch(void* const* d_in, const int* in_sizes, int n_in,
                              void* d_out, int out_size, void* d_ws, size_t ws_size,
                              hipStream_t stream) {
    const float* x = (const float*)d_in[0];
    const float* w = (const float*)d_in[1];
    float* out = (float*)d_out;

    // ws: [wpk 256K][e2n 4K][e2 4K]
    __bf16* wpk = (__bf16*)d_ws;
    float*  e2n = (float*)((char*)d_ws + 262144);
    float*  e2  = (float*)((char*)d_ws + 266240);

    prep_kernel<<<64, 256, 0, stream>>>(w, wpk, e2n, e2);
    vq_main<<<MTOK / TPB, 256, 0, stream>>>(x, w, wpk, e2n, e2, out);
}

// Round 5
// 152.121 us; speedup vs baseline: 2.5550x; 1.0704x over previous
//
#include <hip/hip_runtime.h>

// VectorQuantizer: B=16,T=8192,D=64,K=1024
// out = [quantized 131072x64 f32][indices 131072 as f32]
// Round 5: 32 tokens/wave -> 1024 blocks = 4 waves/SIMD resident;
// coalesced shuffle-gather epilogue (kills 3x write amplification).
#define MTOK  131072
#define DIMD  64
#define KCODE 1024
#define TPB   128        // tokens per block = 4 waves x 32 tokens

typedef __bf16 bf16x8 __attribute__((ext_vector_type(8)));
typedef float  f32x4  __attribute__((ext_vector_type(4)));

__device__ __forceinline__ f32x4 mfma16(bf16x8 a, bf16x8 b, f32x4 c) {
    return __builtin_amdgcn_mfma_f32_16x16x32_bf16(a, b, c, 0, 0, 0);
}

// ---- prep: pack W into MFMA-fragment order + e2 tables (round-3/4 verified) ----
// wpk element offset = cb*2048 + win*512 + lane*8
// win: 0=hi d0-31, 1=hi d32-63, 2=lo d0-31, 3=lo d32-63 ; lane=(q,m): w[cb*16+m][(win&1)*32+q*8 ..+8]
__global__ __launch_bounds__(256) void prep_kernel(
    const float* __restrict__ w, __bf16* __restrict__ wpk,
    float* __restrict__ e2n, float* __restrict__ e2) {
    int cb  = blockIdx.x;            // 0..63
    int tid = threadIdx.x;
    int win = tid >> 6, lane = tid & 63;
    int q = lane >> 4, m = lane & 15;
    int k = cb * 16 + m;
    int d0 = (win & 1) * 32 + q * 8;
    const float* src = w + (size_t)k * DIMD + d0;
    float4 v0 = *(const float4*)(src);
    float4 v1 = *(const float4*)(src + 4);
    float f[8] = {v0.x, v0.y, v0.z, v0.w, v1.x, v1.y, v1.z, v1.w};
    bf16x8 o;
#pragma unroll
    for (int j = 0; j < 8; ++j) {
        __bf16 h = (__bf16)f[j];
        o[j] = (win < 2) ? h : (__bf16)(f[j] - (float)h);
    }
    *(bf16x8*)(wpk + ((size_t)(cb * 4 + win) * 64 + lane) * 8) = o;

    if (tid < 16) {   // e2 in exact round-1 fma order (matches np argmin, absmax=0)
        int k2 = cb * 16 + tid;
        const float4* row = (const float4*)(w + (size_t)k2 * DIMD);
        float s = 0.f;
#pragma unroll
        for (int i = 0; i < 16; ++i) {
            float4 v = row[i];
            s = fmaf(v.x, v.x, s); s = fmaf(v.y, v.y, s);
            s = fmaf(v.z, v.z, s); s = fmaf(v.w, v.w, s);
        }
        e2[k2]  = s;
        e2n[k2] = -0.5f * s;
    }
}

__global__ __launch_bounds__(256, 4) void vq_main(
    const float* __restrict__ x, const float* __restrict__ wfull,
    const __bf16* __restrict__ wpk, const float* __restrict__ e2n_g,
    const float* __restrict__ e2_g, float* __restrict__ out) {

    const int tid  = threadIdx.x;
    const int blk  = blockIdx.x;
    const int lane = tid & 63;
    const int wv   = tid >> 6;      // wave -> tokens wv*32..+32
    const int q    = lane >> 4;
    const int m    = lane & 15;
    const size_t tok0 = (size_t)blk * TPB + wv * 32;   // wave's first token

    // ---- x fragments straight from global, hi/lo split in registers ----
    bf16x8 bx[2][4];
#pragma unroll
    for (int tg = 0; tg < 2; ++tg) {
        const float* xr = x + (tok0 + tg * 16 + m) * DIMD;
#pragma unroll
        for (int h = 0; h < 2; ++h) {
            float4 v0 = *(const float4*)(xr + h * 32 + q * 8);
            float4 v1 = *(const float4*)(xr + h * 32 + q * 8 + 4);
            float f[8] = {v0.x, v0.y, v0.z, v0.w, v1.x, v1.y, v1.z, v1.w};
            bf16x8 hi, lo;
#pragma unroll
            for (int j = 0; j < 8; ++j) {
                __bf16 hh = (__bf16)f[j];
                hi[j] = hh;
                lo[j] = (__bf16)(f[j] - (float)hh);
            }
            bx[tg][h]     = hi;
            bx[tg][2 + h] = lo;
        }
    }

    float b1[2], b2[2]; int i1[2];
#pragma unroll
    for (int tg = 0; tg < 2; ++tg) { b1[tg] = -3e38f; b2[tg] = -3e38f; i1[tg] = 0; }

    // acc = dot - e2/2 (C-init); argmax(acc) == argmin(dist). Tracker: top-1
    // (value+idx, strict > => ties keep lower code) + top-2 value (med3).
    auto step = [&](bf16x8 f0, bf16x8 f1, bf16x8 f2, bf16x8 f3, f32x4 ee, int cbase) {
#pragma unroll
        for (int tg = 0; tg < 2; ++tg) {
            f32x4 t = mfma16(f0, bx[tg][0], ee);   // w_hi*x_hi d0-31
            t = mfma16(f1, bx[tg][1], t);          // w_hi*x_hi d32-63
            t = mfma16(f0, bx[tg][2], t);          // w_hi*x_lo
            t = mfma16(f1, bx[tg][3], t);
            t = mfma16(f2, bx[tg][0], t);          // w_lo*x_hi
            t = mfma16(f3, bx[tg][1], t);
#pragma unroll
            for (int r = 0; r < 4; ++r) {
                float a   = t[r];
                int idxv  = cbase + q * 4 + r;
                bool gt   = a > b1[tg];
                i1[tg] = gt ? idxv : i1[tg];
                b2[tg] = __builtin_amdgcn_fmed3f(a, b1[tg], b2[tg]);
                b1[tg] = fmaxf(a, b1[tg]);
            }
        }
    };

    // ---- main loop: 64 code-blocks, W frags from L2, 2-deep reg ping-pong ----
    const __bf16* wb = wpk + lane * 8;     // lane-contiguous fragment base
    const float*  eb = e2n_g + q * 4;
    bf16x8 A0 = *(const bf16x8*)(wb + 0);
    bf16x8 A1 = *(const bf16x8*)(wb + 512);
    bf16x8 A2 = *(const bf16x8*)(wb + 1024);
    bf16x8 A3 = *(const bf16x8*)(wb + 1536);
    f32x4  EA = *(const f32x4*)(eb);

    for (int cb = 0; cb < 64; cb += 2) {
        const __bf16* pB = wb + (size_t)(cb + 1) * 2048;
        bf16x8 B0 = *(const bf16x8*)(pB + 0);
        bf16x8 B1 = *(const bf16x8*)(pB + 512);
        bf16x8 B2 = *(const bf16x8*)(pB + 1024);
        bf16x8 B3 = *(const bf16x8*)(pB + 1536);
        f32x4  EB = *(const f32x4*)(eb + (cb + 1) * 16);

        step(A0, A1, A2, A3, EA, cb * 16);

        if (cb + 2 < 64) {
            const __bf16* pA = wb + (size_t)(cb + 2) * 2048;
            A0 = *(const bf16x8*)(pA + 0);
            A1 = *(const bf16x8*)(pA + 512);
            A2 = *(const bf16x8*)(pA + 1024);
            A3 = *(const bf16x8*)(pA + 1536);
            EA = *(const f32x4*)(eb + (cb + 2) * 16);
        }
        step(B0, B1, B2, B3, EB, (cb + 1) * 16);
    }

    // ---- cross-quad merge: lanes m,m+16,m+32,m+48 hold disjoint code sets ----
    float B1f[2], B2f[2]; int I1f[2];
#pragma unroll
    for (int tg = 0; tg < 2; ++tg) {
        float B1 = b1[tg], B2 = b2[tg]; int I1 = i1[tg];
#pragma unroll
        for (int mask = 16; mask <= 32; mask <<= 1) {
            float ob1 = __shfl_xor(B1, mask);
            float ob2 = __shfl_xor(B2, mask);
            int   oi  = __shfl_xor(I1, mask);
            bool take = (ob1 > B1) || (ob1 == B1 && oi < I1);
            B2 = fmaxf(fminf(ob1, B1), fmaxf(ob2, B2));
            I1 = take ? oi : I1;
            B1 = fmaxf(ob1, B1);
        }
        B1f[tg] = B1; B2f[tg] = B2; I1f[tg] = I1;   // replicated across quads
    }

    // token t (0..31) of this wave -> its index; lanes 0..31 own token lane
    int myidx;
    {
        int src = lane & 15;
        int v0 = __shfl(I1f[0], src);
        int v1 = __shfl(I1f[1], src);
        myidx = ((lane >> 4) & 1) ? v1 : v0;
    }

    // ---- ballot-driven exact fp32 rescan of near-ties (round-1 numerics) ----
#pragma unroll
    for (int tg = 0; tg < 2; ++tg) {
        unsigned long long msk =
            __ballot((lane < 16) && (B1f[tg] - B2f[tg] < 2e-3f));
        while (msk) {
            int mm = __ffsll((unsigned long long)msk) - 1;
            msk &= msk - 1;
            int tloc = tg * 16 + mm;              // token within this wave (0..31)
            const float4* xr = (const float4*)(x + (tok0 + tloc) * DIMD);
            float bv = 3e38f; int bi = 0;
            for (int j = 0; j < 16; ++j) {
                int k = lane * 16 + j;
                const float4* wr = (const float4*)(wfull + (size_t)k * DIMD);
                float s = 0.f;
#pragma unroll
                for (int i = 0; i < 16; ++i) {
                    float4 xv = xr[i], wv4 = wr[i];
                    s = fmaf(xv.x, wv4.x, s); s = fmaf(xv.y, wv4.y, s);
                    s = fmaf(xv.z, wv4.z, s); s = fmaf(xv.w, wv4.w, s);
                }
                float dv = fmaf(-2.f, s, e2_g[k]);
                if (dv < bv) { bv = dv; bi = k; }  // ties -> lower k
            }
#pragma unroll
            for (int mask2 = 1; mask2 <= 32; mask2 <<= 1) {
                float ov = __shfl_xor(bv, mask2);
                int   oi = __shfl_xor(bi, mask2);
                bool take = (ov < bv) || (ov == bv && oi < bi);
                bv = take ? ov : bv;
                bi = take ? oi : bi;
            }
            myidx = (lane == tloc) ? bi : myidx;
        }
    }

    // ---- outputs ----
    // indices as f32 (lanes 0..31 own tokens 0..31 of this wave)
    if (lane < 32)
        out[(size_t)MTOK * DIMD + tok0 + lane] = (float)myidx;

    // coalesced gather: per j, wave writes one contiguous 1KB segment;
    // codebook row read cooperatively (16 lanes per row, contiguous 256B)
    {
        float* obase = out + tok0 * DIMD;
#pragma unroll
        for (int j = 0; j < 8; ++j) {
            int srcl = j * 4 + (lane >> 4);        // token 0..31
            int gi   = __shfl(myidx, srcl);
            float4 v = *(const float4*)(wfull + (size_t)gi * DIMD + (lane & 15) * 4);
            *(float4*)(obase + j * 256 + lane * 4) = v;
        }
    }
}

extern "C" void kernel_launch(void* const* d_in, const int* in_sizes, int n_in,
                              void* d_out, int out_size, void* d_ws, size_t ws_size,
                              hipStream_t stream) {
    const float* x = (const float*)d_in[0];
    const float* w = (const float*)d_in[1];
    float* out = (float*)d_out;

    // ws: [wpk 256K][e2n 4K][e2 4K]
    __bf16* wpk = (__bf16*)d_ws;
    float*  e2n = (float*)((char*)d_ws + 262144);
    float*  e2  = (float*)((char*)d_ws + 266240);

    prep_kernel<<<64, 256, 0, stream>>>(w, wpk, e2n, e2);
    vq_main<<<MTOK / TPB, 256, 0, stream>>>(x, w, wpk, e2n, e2, out);
}